// Round 13
// baseline (707.283 us; speedup 1.0000x reference)
//
#include <hip/hip_runtime.h>
#include <hip/hip_bf16.h>

// B=8, T=2048, D=2048.
//   avg = cumsum(x, axis=T) / (t+1)
//   gates = concat(x, avg) @ W^T + b    (W: [4096][4096])
//   out0 = sig(gates[:, :2048]) * x + sig(gates[:, 2048:]) * avg
// outputs: [out0 fp32] ++ [avg fp32]

#define Bb 8
#define Tt 2048
#define Dd 2048
#define Mm (Bb * Tt)       // 16384
#define Kk 4096
#define NC 32
#define CT 64

typedef __bf16 bf16x8 __attribute__((ext_vector_type(8)));
typedef float f32x4 __attribute__((ext_vector_type(4)));

__device__ __forceinline__ void gload16(const void* g, void* l) {
    __builtin_amdgcn_global_load_lds(
        (const __attribute__((address_space(1))) unsigned int*)g,
        (__attribute__((address_space(3))) unsigned int*)l, 16, 0, 0);
}

// ---------------- K1: W fp32 -> bf16 ----------------
__global__ void wconv_kernel(const float* __restrict__ W,
                             unsigned short* __restrict__ Wb, long n) {
    long i = ((long)blockIdx.x * blockDim.x + threadIdx.x) * 4;
    long stride = (long)gridDim.x * blockDim.x * 4;
    for (; i < n; i += stride) {
        float4 v = *(const float4*)(W + i);
        __hip_bfloat16 a = __float2bfloat16(v.x);
        __hip_bfloat16 b = __float2bfloat16(v.y);
        __hip_bfloat16 c = __float2bfloat16(v.z);
        __hip_bfloat16 d = __float2bfloat16(v.w);
        ushort4 u;
        u.x = *(unsigned short*)&a; u.y = *(unsigned short*)&b;
        u.z = *(unsigned short*)&c; u.w = *(unsigned short*)&d;
        *(ushort4*)(Wb + i) = u;
    }
}

// ---------------- K2: per-chunk sums ----------------
__global__ void ksum_kernel(const float* __restrict__ X, float* __restrict__ S) {
    int d = blockIdx.y * 256 + threadIdx.x;
    int bc = blockIdx.x;
    int b = bc >> 5, c = bc & 31;
    const float* p = X + ((long)(b * Tt + c * CT)) * Dd + d;
    float s = 0.f;
#pragma unroll 8
    for (int t = 0; t < CT; ++t) s += p[(long)t * Dd];
    S[(long)bc * Dd + d] = s;
}

// ---------------- K3: scan + emit avg fp32 + gating_in bf16 ----------------
__global__ void kscan_kernel(const float* __restrict__ X, const float* __restrict__ S,
                             float* __restrict__ AVG, unsigned short* __restrict__ Gin) {
    int d = blockIdx.y * 256 + threadIdx.x;
    int bc = blockIdx.x;
    int b = bc >> 5, c = bc & 31;
    const float* Sp = S + (long)(b * NC) * Dd + d;
    float run = 0.f;
    for (int cc = 0; cc < c; ++cc) run += Sp[(long)cc * Dd];
    const float* p = X + ((long)(b * Tt + c * CT)) * Dd + d;
    long row = (long)b * Tt + c * CT;
    for (int tt = 0; tt < CT; ++tt) {
        float x = p[(long)tt * Dd];
        run += x;
        float av = run / (float)(c * CT + tt + 1);
        long r = row + tt;
        AVG[r * Dd + d] = av;
        __hip_bfloat16 xb = __float2bfloat16(x);
        __hip_bfloat16 ab = __float2bfloat16(av);
        Gin[r * 4096 + d] = *(unsigned short*)&xb;
        Gin[r * 4096 + 2048 + d] = *(unsigned short*)&ab;
    }
}

// ---------------- K4: 8-wave 256x(128d x 2 gates), BK=32, 2 blocks/CU -------
// R6's proven 2-phase m201-style body, but: 2-deep buffer (2 x 32KB = 64KB
// LDS) + __launch_bounds__(512,2) -> 2 blocks/CU. Staging distance 1,
// boundary vmcnt(0): the drain is hidden by the SIBLING block's MFMA work
// (m114 wave-level overlap), instead of stalling the whole CU as in the
// 1-block variants. Same 0-conflict swizzle / mapping / fused epilogue.
#define MFMA(va, vb, c_) c_ = __builtin_amdgcn_mfma_f32_16x16x32_bf16(va, vb, c_, 0, 0, 0)
#define RD(p_, i_) (*(const bf16x8*)((p_) + (i_) * 1024))
#define SBAR __builtin_amdgcn_s_barrier()
#define SCHB __builtin_amdgcn_sched_barrier(0)

#define TILEBODY(t_, bb_, STG_)                                                 \
  {                                                                             \
    const char* pa_ = rA0 + (bb_);                                              \
    const char* pb_ = rB0 + (bb_);                                              \
    char* nb_ = ldsb + ((bb_) ^ 32768) + woff;                                  \
    const long ko_ = ((long)(t_) + 1) * 64;                                     \
    /* ---- phase 0: reads A0-3,B0-3; stage A(t+1); MFMA mi0-3 ---- */          \
    bf16x8 a0 = RD(pa_,0), a1 = RD(pa_,1), a2 = RD(pa_,2), a3 = RD(pa_,3);      \
    bf16x8 b0 = RD(pb_,0), b1 = RD(pb_,1), b2 = RD(pb_,2), b3 = RD(pb_,3);      \
    if (STG_) { gload16(gA0 + ko_, nb_); gload16(gA1 + ko_, nb_ + 8192); }      \
    SCHB; SBAR;                                                                 \
    asm volatile("s_waitcnt lgkmcnt(0)" ::: "memory"); SCHB;                    \
    __builtin_amdgcn_s_setprio(1);                                              \
    MFMA(a0,b0,acc[0][0]); MFMA(a0,b1,acc[0][1]); MFMA(a0,b2,acc[0][2]); MFMA(a0,b3,acc[0][3]); \
    MFMA(a1,b0,acc[1][0]); MFMA(a1,b1,acc[1][1]); MFMA(a1,b2,acc[1][2]); MFMA(a1,b3,acc[1][3]); \
    MFMA(a2,b0,acc[2][0]); MFMA(a2,b1,acc[2][1]); MFMA(a2,b2,acc[2][2]); MFMA(a2,b3,acc[2][3]); \
    MFMA(a3,b0,acc[3][0]); MFMA(a3,b1,acc[3][1]); MFMA(a3,b2,acc[3][2]); MFMA(a3,b3,acc[3][3]); \
    __builtin_amdgcn_s_setprio(0); SCHB; SBAR;                                  \
    /* ---- phase 1: reads A4-7; stage B(t+1); MFMA mi4-7; boundary ---- */     \
    bf16x8 a4 = RD(pa_,4), a5 = RD(pa_,5), a6 = RD(pa_,6), a7 = RD(pa_,7);      \
    if (STG_) { gload16(gB0 + ko_, nb_ + 16384); gload16(gB1 + ko_, nb_ + 24576); } \
    SCHB; SBAR;                                                                 \
    asm volatile("s_waitcnt lgkmcnt(0)" ::: "memory"); SCHB;                    \
    __builtin_amdgcn_s_setprio(1);                                              \
    MFMA(a4,b0,acc[4][0]); MFMA(a4,b1,acc[4][1]); MFMA(a4,b2,acc[4][2]); MFMA(a4,b3,acc[4][3]); \
    MFMA(a5,b0,acc[5][0]); MFMA(a5,b1,acc[5][1]); MFMA(a5,b2,acc[5][2]); MFMA(a5,b3,acc[5][3]); \
    MFMA(a6,b0,acc[6][0]); MFMA(a6,b1,acc[6][1]); MFMA(a6,b2,acc[6][2]); MFMA(a6,b3,acc[6][3]); \
    MFMA(a7,b0,acc[7][0]); MFMA(a7,b1,acc[7][1]); MFMA(a7,b2,acc[7][2]); MFMA(a7,b3,acc[7][3]); \
    __builtin_amdgcn_s_setprio(0); SCHB;                                        \
    asm volatile("s_waitcnt vmcnt(0)" ::: "memory");                            \
    SBAR; SCHB;                                                                 \
  }

__global__ __launch_bounds__(512, 2) void gemm2b_kernel(
    const unsigned short* __restrict__ Gin,  // [16384][4096] bf16
    const unsigned short* __restrict__ Wb,   // [4096][4096] bf16
    const float* __restrict__ bias,          // [4096]
    float* __restrict__ OUT)                 // [16384][2048]
{
    __shared__ __attribute__((aligned(128))) char lds[65536]; // 2 x (A16K+B16K)
    char* ldsb = (char*)lds;

    const int tid = threadIdx.x;
    const int w = tid >> 6, l = tid & 63;
    const int wm = w >> 2, wn = w & 3;       // 2(M) x 4(N) waves
    const int lm = l & 15;
    const int woff = w * 1024;

    // Batch-aware mapping (FETCH-proven): 256-block rounds = 16 m-tiles x
    // 16 n-tiles (A 32MB + W 32MB < L3); per XCD 2 n-tiles (B panel -> L2).
    const int bid = blockIdx.x;
    const int batch = bid >> 8;
    const int rr = bid & 255;
    const int xcd = rr & 7;
    const int j = rr >> 3;
    const int nt = xcd * 2 + (j >> 4);
    const int mt = batch * 16 + (j & 15);
    const long m0 = (long)mt * 256;
    const int n0 = nt * 128;

    // ---- staging addresses (pre-swizzled global chunk; LDS dest linear) ----
    const int srow = tid >> 2;
    const int schunk = (tid & 3) ^ ((tid >> 3) & 3);
    const char* gA0 = (const char*)Gin + (m0 + srow) * 8192 + schunk * 16;
    const char* gA1 = gA0 + 128 * 8192;
    // B tile row j (0..255) -> W row: d-block (j>>6)*32 + (j&31), gate (j>>5)&1
    const long jr0 = n0 + ((srow >> 6) << 5) + (srow & 31) + (((srow >> 5) & 1) << 11);
    const int j1 = 128 + srow;
    const long jr1 = n0 + ((j1 >> 6) << 5) + (j1 & 31) + (((j1 >> 5) & 1) << 11);
    const char* gB0 = (const char*)Wb + jr0 * 8192 + schunk * 16;
    const char* gB1 = (const char*)Wb + jr1 * 8192 + schunk * 16;

    // ---- read addresses (proven 0-conflict swizzle) ----
    const int cbyte = (((l >> 4) ^ ((lm >> 1) & 3))) * 16;
    const char* rA0 = ldsb + (wm * 128 + lm) * 64 + cbyte;          // +buf +mi*1024
    const char* rB0 = ldsb + 16384 + (wn * 64 + lm) * 64 + cbyte;   // +buf +nj*1024

    f32x4 acc[8][4] = {};   // [mi][nj]: nj 0-1 gate-i, 2-3 gate-f

    // prologue: stage tile 0 into buf0
    gload16(gA0, ldsb + woff);
    gload16(gA1, ldsb + 8192 + woff);
    gload16(gB0, ldsb + 16384 + woff);
    gload16(gB1, ldsb + 24576 + woff);
    asm volatile("s_waitcnt vmcnt(0)" ::: "memory");
    SBAR; SCHB;

#pragma unroll 1
    for (int t = 0; t < 126; t += 2) {    // stages tiles 1..126
        TILEBODY(t,     0,     1)
        TILEBODY(t + 1, 32768, 1)
    }
    TILEBODY(126, 0,     1)               // stages tile 127
    TILEBODY(127, 32768, 0)               // tail: no stage

    // ---- fused epilogue (bf16 x/avg from Gin; C/D: col=l&15, row=(l>>4)*4+r)
#pragma unroll
    for (int mi = 0; mi < 8; ++mi) {
        long rbase = m0 + wm * 128 + mi * 16 + (l >> 4) * 4;
#pragma unroll
        for (int nj = 0; nj < 2; ++nj) {
            int d = n0 + wn * 32 + nj * 16 + lm;
            float bi_ = bias[d];
            float bf_ = bias[d + 2048];
#pragma unroll
            for (int r = 0; r < 4; ++r) {
                long row = rbase + r;
                unsigned int ux = Gin[row * 4096 + d];
                unsigned int ua = Gin[row * 4096 + 2048 + d];
                union { unsigned int u; float f; } cx, ca;
                cx.u = ux << 16; ca.u = ua << 16;
                float gi = acc[mi][nj][r] + bi_;
                float gf = acc[mi][nj + 2][r] + bf_;
                float si = 1.f / (1.f + __expf(-gi));
                float sf = 1.f / (1.f + __expf(-gf));
                OUT[row * 2048 + d] = si * cx.f + sf * ca.f;
            }
        }
    }
}

extern "C" void kernel_launch(void* const* d_in, const int* in_sizes, int n_in,
                              void* d_out, int out_size, void* d_ws, size_t ws_size,
                              hipStream_t stream) {
    const float* X = (const float*)d_in[0];     // layer_in [8][2048][2048]
    const float* W = (const float*)d_in[1];     // W_gate [4096][4096]
    const float* bias = (const float*)d_in[2];  // b_gate [4096]

    float* OUT = (float*)d_out;                 // gating_out
    float* AVG = OUT + (long)Mm * Dd;           // average_out

    char* ws = (char*)d_ws;
    unsigned short* Wb  = (unsigned short*)ws;                    // 33,554,432 B
    unsigned short* Gin = (unsigned short*)(ws + 33554432);       // 134,217,728 B
    float* S = (float*)(ws + 33554432 + 134217728);               // 2,097,152 B

    wconv_kernel<<<2048, 256, 0, stream>>>(W, Wb, (long)Kk * Kk);
    ksum_kernel<<<dim3(Bb * NC, Dd / 256), 256, 0, stream>>>(X, S);
    kscan_kernel<<<dim3(Bb * NC, Dd / 256), 256, 0, stream>>>(X, S, AVG, Gin);
    gemm2b_kernel<<<1024, 512, 0, stream>>>(Gin, Wb, bias, OUT);
}

// Round 15
// 597.355 us; speedup vs baseline: 1.1840x; 1.1840x over previous
//
#include <hip/hip_runtime.h>
#include <hip/hip_bf16.h>

// B=8, T=2048, D=2048.
//   avg = cumsum(x, axis=T) / (t+1)
//   gates = concat(x, avg) @ W^T + b    (W: [4096][4096])
//   out0 = sig(gates[:, :2048]) * x + sig(gates[:, 2048:]) * avg
// outputs: [out0 fp32] ++ [avg fp32]

#define Bb 8
#define Tt 2048
#define Dd 2048
#define Mm (Bb * Tt)       // 16384
#define Kk 4096
#define NC 32
#define CT 64

typedef __bf16 bf16x8 __attribute__((ext_vector_type(8)));
typedef float f32x4 __attribute__((ext_vector_type(4)));

__device__ __forceinline__ void gload16(const void* g, void* l) {
    __builtin_amdgcn_global_load_lds(
        (const __attribute__((address_space(1))) unsigned int*)g,
        (__attribute__((address_space(3))) unsigned int*)l, 16, 0, 0);
}

// ---------------- K1: W fp32 -> bf16 ----------------
__global__ void wconv_kernel(const float* __restrict__ W,
                             unsigned short* __restrict__ Wb, long n) {
    long i = ((long)blockIdx.x * blockDim.x + threadIdx.x) * 4;
    long stride = (long)gridDim.x * blockDim.x * 4;
    for (; i < n; i += stride) {
        float4 v = *(const float4*)(W + i);
        __hip_bfloat16 a = __float2bfloat16(v.x);
        __hip_bfloat16 b = __float2bfloat16(v.y);
        __hip_bfloat16 c = __float2bfloat16(v.z);
        __hip_bfloat16 d = __float2bfloat16(v.w);
        ushort4 u;
        u.x = *(unsigned short*)&a; u.y = *(unsigned short*)&b;
        u.z = *(unsigned short*)&c; u.w = *(unsigned short*)&d;
        *(ushort4*)(Wb + i) = u;
    }
}

// ---------------- K2: per-chunk sums + emit bf16 x-half of Gin --------------
// Fused: during the (already required) X read, write the bf16 cast of x into
// Gin's x-half. K3 then reads bf16 (67MB) instead of fp32 X (134MB) and skips
// the x-half write. Net pre-pass HBM saving ~67MB.
__global__ void ksum_kernel(const float* __restrict__ X, float* __restrict__ S,
                            unsigned short* __restrict__ Gin) {
    int d = blockIdx.y * 256 + threadIdx.x;
    int bc = blockIdx.x;
    int b = bc >> 5, c = bc & 31;
    const float* p = X + ((long)(b * Tt + c * CT)) * Dd + d;
    long row = (long)b * Tt + c * CT;
    float s = 0.f;
#pragma unroll 8
    for (int t = 0; t < CT; ++t) {
        float x = p[(long)t * Dd];
        s += x;
        __hip_bfloat16 xb = __float2bfloat16(x);
        Gin[(row + t) * 4096 + d] = *(unsigned short*)&xb;
    }
    S[(long)bc * Dd + d] = s;
}

// ---------------- K3: scan (bf16 x) + emit avg fp32 + Gin avg-half ----------
__global__ void kscan_kernel(const unsigned short* __restrict__ Ginx,
                             const float* __restrict__ S,
                             float* __restrict__ AVG, unsigned short* __restrict__ Gin) {
    int d = blockIdx.y * 256 + threadIdx.x;
    int bc = blockIdx.x;
    int b = bc >> 5, c = bc & 31;
    const float* Sp = S + (long)(b * NC) * Dd + d;
    float run = 0.f;
    for (int cc = 0; cc < c; ++cc) run += Sp[(long)cc * Dd];
    long row = (long)b * Tt + c * CT;
    for (int tt = 0; tt < CT; ++tt) {
        long r = row + tt;
        union { unsigned int u; float f; } cx;
        cx.u = ((unsigned int)Ginx[r * 4096 + d]) << 16;
        run += cx.f;
        float av = run / (float)(c * CT + tt + 1);
        AVG[r * Dd + d] = av;
        __hip_bfloat16 ab = __float2bfloat16(av);
        Gin[r * 4096 + 2048 + d] = *(unsigned short*)&ab;
    }
}

// ---------------- K4: 8-wave 256x(128d x 2 gates), BK=64, pipelined reads ---
// R8 verbatim (best measured: 483us GEMM, MfmaUtil 54%, 0 conflicts).
// ds_reads for phase p+1 issue BEFORE phase p's MFMA cluster; 2 barriers/tile:
//   mid vmcnt(2)+barrier (kk1(t) visible), boundary vmcnt(4)+barrier (kk0(t+1)).
// vm FIFO invariant at tile entry: [Akk1(t)x2, Bkk1(t)x2] outstanding.
#define MFMA(va, vb, c_) c_ = __builtin_amdgcn_mfma_f32_16x16x32_bf16(va, vb, c_, 0, 0, 0)
#define RD(p_, i_) (*(const bf16x8*)((p_) + (i_) * 1024))
#define SBAR __builtin_amdgcn_s_barrier()
#define SCHB __builtin_amdgcn_sched_barrier(0)
#define LGKM0 do { asm volatile("s_waitcnt lgkmcnt(0)" ::: "memory"); SCHB; } while (0)

#define CL_LO(B0_, B1_, B2_, B3_)                                               \
    __builtin_amdgcn_s_setprio(1);                                              \
    MFMA(aL0,B0_,acc[0][0]); MFMA(aL0,B1_,acc[0][1]); MFMA(aL0,B2_,acc[0][2]); MFMA(aL0,B3_,acc[0][3]); \
    MFMA(aL1,B0_,acc[1][0]); MFMA(aL1,B1_,acc[1][1]); MFMA(aL1,B2_,acc[1][2]); MFMA(aL1,B3_,acc[1][3]); \
    MFMA(aL2,B0_,acc[2][0]); MFMA(aL2,B1_,acc[2][1]); MFMA(aL2,B2_,acc[2][2]); MFMA(aL2,B3_,acc[2][3]); \
    MFMA(aL3,B0_,acc[3][0]); MFMA(aL3,B1_,acc[3][1]); MFMA(aL3,B2_,acc[3][2]); MFMA(aL3,B3_,acc[3][3]); \
    __builtin_amdgcn_s_setprio(0);
#define CL_HI(B0_, B1_, B2_, B3_)                                               \
    __builtin_amdgcn_s_setprio(1);                                              \
    MFMA(aH0,B0_,acc[4][0]); MFMA(aH0,B1_,acc[4][1]); MFMA(aH0,B2_,acc[4][2]); MFMA(aH0,B3_,acc[4][3]); \
    MFMA(aH1,B0_,acc[5][0]); MFMA(aH1,B1_,acc[5][1]); MFMA(aH1,B2_,acc[5][2]); MFMA(aH1,B3_,acc[5][3]); \
    MFMA(aH2,B0_,acc[6][0]); MFMA(aH2,B1_,acc[6][1]); MFMA(aH2,B2_,acc[6][2]); MFMA(aH2,B3_,acc[6][3]); \
    MFMA(aH3,B0_,acc[7][0]); MFMA(aH3,B1_,acc[7][1]); MFMA(aH3,B2_,acc[7][2]); MFMA(aH3,B3_,acc[7][3]); \
    __builtin_amdgcn_s_setprio(0);

#define TILE64(t_, bb_, STG_, VM_, VB_)                                         \
  {                                                                             \
    const char* pa_ = rA0 + (bb_);                                              \
    const char* pb_ = rB0 + (bb_);                                              \
    char* nb_ = ldsb + ((bb_) ^ 65536) + woff;                                  \
    const long ko_ = ((long)(t_) + 1) * 128;                                    \
    /* tile start: X = kk0 lo-A + kk0 B; stage Akk0(t+1) */                     \
    aL0 = RD(pa_,0); aL1 = RD(pa_,1); aL2 = RD(pa_,2); aL3 = RD(pa_,3);         \
    bb0 = RD(pb_,0); bb1 = RD(pb_,1); bb2 = RD(pb_,2); bb3 = RD(pb_,3);         \
    if (STG_) { gload16(gA0 + ko_, nb_); gload16(gA1 + ko_, nb_ + 8192); }      \
    LGKM0;                                      /* X ready */                   \
    /* PH0: issue Y = kk0 hi-A; MFMA lo-kk0 */                                  \
    aH0 = RD(pa_,4); aH1 = RD(pa_,5); aH2 = RD(pa_,6); aH3 = RD(pa_,7);         \
    SCHB;                                                                       \
    CL_LO(bb0, bb1, bb2, bb3)                                                   \
    SCHB;                                                                       \
    asm volatile("s_waitcnt vmcnt(" #VM_ ")" ::: "memory");                     \
    SBAR; SCHB;                                 /* kk1(t) visible */            \
    LGKM0;                                      /* Y ready */                   \
    /* PH1: issue Z = kk1 lo-A + kk1 B; stage Bkk0(t+1); MFMA hi-kk0 */         \
    aL0 = RD(pa_+32768,0); aL1 = RD(pa_+32768,1); aL2 = RD(pa_+32768,2); aL3 = RD(pa_+32768,3); \
    bd0 = RD(pb_+32768,0); bd1 = RD(pb_+32768,1); bd2 = RD(pb_+32768,2); bd3 = RD(pb_+32768,3); \
    if (STG_) { gload16(gB0 + ko_, nb_ + 16384); gload16(gB1 + ko_, nb_ + 24576); } \
    SCHB;                                                                       \
    CL_HI(bb0, bb1, bb2, bb3)                                                   \
    SCHB;                                                                       \
    LGKM0;                                      /* Z ready */                   \
    /* PH2: issue W = kk1 hi-A; stage Akk1(t+1); MFMA lo-kk1 */                 \
    aH0 = RD(pa_+32768,4); aH1 = RD(pa_+32768,5); aH2 = RD(pa_+32768,6); aH3 = RD(pa_+32768,7); \
    if (STG_) { gload16(gA0 + ko_ + 64, nb_ + 32768); gload16(gA1 + ko_ + 64, nb_ + 40960); } \
    SCHB;                                                                       \
    CL_LO(bd0, bd1, bd2, bd3)                                                   \
    SCHB;                                                                       \
    LGKM0;                                      /* W ready */                   \
    /* PH3: stage Bkk1(t+1); MFMA hi-kk1 */                                     \
    if (STG_) { gload16(gB0 + ko_ + 64, nb_ + 49152); gload16(gB1 + ko_ + 64, nb_ + 57344); } \
    SCHB;                                                                       \
    CL_HI(bd0, bd1, bd2, bd3)                                                   \
    SCHB;                                                                       \
    asm volatile("s_waitcnt vmcnt(" #VB_ ")" ::: "memory");                     \
    SBAR; SCHB;                                 /* kk0(t+1) visible */          \
  }

__global__ __launch_bounds__(512, 1) void gemmsp_kernel(
    const unsigned short* __restrict__ Gin,  // [16384][4096] bf16
    const unsigned short* __restrict__ Wb,   // [4096][4096] bf16
    const float* __restrict__ bias,          // [4096]
    float* __restrict__ OUT)                 // [16384][2048]
{
    __shared__ __attribute__((aligned(128))) char lds[131072]; // 2 x 64KB
    char* ldsb = (char*)lds;

    const int tid = threadIdx.x;
    const int w = tid >> 6, l = tid & 63;
    const int wm = w >> 2, wn = w & 3;       // 2(M) x 4(N) waves
    const int lm = l & 15;
    const int woff = w * 1024;

    // Batch-aware mapping (FETCH-proven): 256-block rounds = 16 m-tiles x
    // 16 n-tiles (A 32MB + W 32MB < L3); per XCD 2 n-tiles (B panel -> L2).
    const int bid = blockIdx.x;
    const int batch = bid >> 8;
    const int rr = bid & 255;
    const int xcd = rr & 7;
    const int j = rr >> 3;
    const int nt = xcd * 2 + (j >> 4);
    const int mt = batch * 16 + (j & 15);
    const long m0 = (long)mt * 256;
    const int n0 = nt * 128;

    // ---- staging addresses (pre-swizzled global chunk; LDS dest linear) ----
    const int srow = tid >> 2;
    const int schunk = (tid & 3) ^ ((tid >> 3) & 3);
    const char* gA0 = (const char*)Gin + (m0 + srow) * 8192 + schunk * 16;
    const char* gA1 = gA0 + 128 * 8192;
    // B tile row j (0..255) -> W row: d-block (j>>6)*32 + (j&31), gate (j>>5)&1
    const long jr0 = n0 + ((srow >> 6) << 5) + (srow & 31) + (((srow >> 5) & 1) << 11);
    const int j1 = 128 + srow;
    const long jr1 = n0 + ((j1 >> 6) << 5) + (j1 & 31) + (((j1 >> 5) & 1) << 11);
    const char* gB0 = (const char*)Wb + jr0 * 8192 + schunk * 16;
    const char* gB1 = (const char*)Wb + jr1 * 8192 + schunk * 16;

    // ---- read addresses (proven 0-conflict swizzle) ----
    const int cbyte = (((l >> 4) ^ ((lm >> 1) & 3))) * 16;
    const char* rA0 = ldsb + (wm * 128 + lm) * 64 + cbyte;          // +bb +kk*32768 +mi*1024
    const char* rB0 = ldsb + 16384 + (wn * 64 + lm) * 64 + cbyte;   // +bb +kk*32768 +nj*1024

    f32x4 acc[8][4] = {};   // [mi][nj]: nj 0-1 gate-i, 2-3 gate-f

    // rotating operand registers
    bf16x8 aL0, aL1, aL2, aL3, aH0, aH1, aH2, aH3;
    bf16x8 bb0, bb1, bb2, bb3, bd0, bd1, bd2, bd3;

    // prologue: stage tile 0 (Akk0, Bkk0, Akk1, Bkk1) into buf0
    gload16(gA0,      ldsb + woff);
    gload16(gA1,      ldsb + 8192 + woff);
    gload16(gB0,      ldsb + 16384 + woff);
    gload16(gB1,      ldsb + 24576 + woff);
    gload16(gA0 + 64, ldsb + 32768 + woff);
    gload16(gA1 + 64, ldsb + 40960 + woff);
    gload16(gB0 + 64, ldsb + 49152 + woff);
    gload16(gB1 + 64, ldsb + 57344 + woff);
    asm volatile("s_waitcnt vmcnt(4)" ::: "memory");   // kk0 landed; kk1 in flight
    SBAR; SCHB;

#pragma unroll 1
    for (int t = 0; t < 62; t += 2) {     // stages tiles 1..62
        TILE64(t,     0,     1, 2, 4)
        TILE64(t + 1, 65536, 1, 2, 4)
    }
    TILE64(62, 0,     1, 2, 4)            // stages tile 63
    TILE64(63, 65536, 0, 0, 0)            // tail: drain

    // ---- fused epilogue (bf16 x/avg from Gin; C/D: col=l&15, row=(l>>4)*4+r)
#pragma unroll
    for (int mi = 0; mi < 8; ++mi) {
        long rbase = m0 + wm * 128 + mi * 16 + (l >> 4) * 4;
#pragma unroll
        for (int nj = 0; nj < 2; ++nj) {
            int d = n0 + wn * 32 + nj * 16 + lm;
            float bi_ = bias[d];
            float bf_ = bias[d + 2048];
#pragma unroll
            for (int r = 0; r < 4; ++r) {
                long row = rbase + r;
                unsigned int ux = Gin[row * 4096 + d];
                unsigned int ua = Gin[row * 4096 + 2048 + d];
                union { unsigned int u; float f; } cx, ca;
                cx.u = ux << 16; ca.u = ua << 16;
                float gi = acc[mi][nj][r] + bi_;
                float gf = acc[mi][nj + 2][r] + bf_;
                float si = 1.f / (1.f + __expf(-gi));
                float sf = 1.f / (1.f + __expf(-gf));
                OUT[row * 2048 + d] = si * cx.f + sf * ca.f;
            }
        }
    }
}

extern "C" void kernel_launch(void* const* d_in, const int* in_sizes, int n_in,
                              void* d_out, int out_size, void* d_ws, size_t ws_size,
                              hipStream_t stream) {
    const float* X = (const float*)d_in[0];     // layer_in [8][2048][2048]
    const float* W = (const float*)d_in[1];     // W_gate [4096][4096]
    const float* bias = (const float*)d_in[2];  // b_gate [4096]

    float* OUT = (float*)d_out;                 // gating_out
    float* AVG = OUT + (long)Mm * Dd;           // average_out

    char* ws = (char*)d_ws;
    unsigned short* Wb  = (unsigned short*)ws;                    // 33,554,432 B
    unsigned short* Gin = (unsigned short*)(ws + 33554432);       // 134,217,728 B
    float* S = (float*)(ws + 33554432 + 134217728);               // 2,097,152 B

    wconv_kernel<<<2048, 256, 0, stream>>>(W, Wb, (long)Kk * Kk);
    ksum_kernel<<<dim3(Bb * NC, Dd / 256), 256, 0, stream>>>(X, S, Gin);
    kscan_kernel<<<dim3(Bb * NC, Dd / 256), 256, 0, stream>>>(Gin, S, AVG, Gin);
    gemmsp_kernel<<<1024, 512, 0, stream>>>(Gin, Wb, bias, OUT);
}